// Round 9
// baseline (1435.507 us; speedup 1.0000x reference)
//
#include <hip/hip_runtime.h>
#include <cstddef>

constexpr int B_ = 64, S_ = 512, E_ = 512, H_ = 8, D_ = 64, L_ = 4, O_ = 1000;
constexpr int BS_ = B_ * S_;        // 32768
constexpr int HD_ = H_ * D_;        // 512
constexpr int QS_ = 1536;           // fused QKV row stride
constexpr int LOUT_ = 102;
constexpr float SCALE_ = 0.04419417382415922f;  // 1/sqrt(512)

typedef __bf16 bf16x8 __attribute__((ext_vector_type(8)));
typedef __bf16 bf16x4 __attribute__((ext_vector_type(4)));
typedef __bf16 bf16x2 __attribute__((ext_vector_type(2)));
typedef float floatx4 __attribute__((ext_vector_type(4)));

__device__ inline void load16_lds(const __bf16* g, __bf16* l) {
  __builtin_amdgcn_global_load_lds(
      (const __attribute__((address_space(1))) void*)g,
      (__attribute__((address_space(3))) void*)l, 16, 0, 0);
}

// ---------------- weight transpose + bf16 convert ----------------
__global__ __launch_bounds__(256) void transpose_bf16(
    const float* __restrict__ in, __bf16* __restrict__ out,
    int R, int C, int IZ, int OZL, int OZH) {
  __shared__ float t[32][33];
  int z = blockIdx.z;
  const float* inz = in + (size_t)z * IZ;
  __bf16* outz = out + (size_t)(z >> 3) * OZL + (size_t)(z & 7) * OZH;
  int c0 = blockIdx.x * 32, r0 = blockIdx.y * 32;
  int x = threadIdx.x, y = threadIdx.y;  // (32,8)
#pragma unroll
  for (int j = 0; j < 32; j += 8) t[y + j][x] = inz[(size_t)(r0 + y + j) * C + c0 + x];
  __syncthreads();
#pragma unroll
  for (int j = 0; j < 32; j += 8)
    outz[(size_t)(c0 + y + j) * R + r0 + x] = (__bf16)t[x][y + j];
}

// ---------------- concat qkv bias: [L][1536] = bq|bk|bv ----------------
__global__ __launch_bounds__(256) void bias_concat(
    const float* __restrict__ bq, const float* __restrict__ bk,
    const float* __restrict__ bv, float* __restrict__ qkvb) {
  int idx = blockIdx.x * 256 + threadIdx.x;  // < 6144
  int l = idx / QS_, j = idx % QS_;
  float v;
  if (j < 512) v = bq[l * 512 + j];
  else if (j < 1024) v = bk[l * 512 + j - 512];
  else v = bv[l * 512 + j - 1024];
  qkvb[idx] = v;
}

// ---------------- embedding + mask -> X fp32 + Ab bf16 ----------------
__global__ __launch_bounds__(256) void embed_kernel(
    const int* __restrict__ tokens, const float* __restrict__ emb,
    float* __restrict__ X, __bf16* __restrict__ Ab) {
  int idx = blockIdx.x * 256 + threadIdx.x;  // float4 index
  int bs = idx >> 7;
  int e = (idx & 127) << 2;
  int tok = tokens[bs];
  float4 v;
  if (tok == 0) v = make_float4(0.f, 0.f, 0.f, 0.f);
  else v = *(const float4*)(emb + (size_t)tok * E_ + e);
  size_t off = (size_t)bs * E_ + e;
  *(float4*)(X + off) = v;
  bf16x4 b;
  b[0] = (__bf16)v.x; b[1] = (__bf16)v.y; b[2] = (__bf16)v.z; b[3] = (__bf16)v.w;
  *(bf16x4*)(Ab + off) = b;
}

// ---------------- bf16 MFMA GEMM, ring-2 LDS + counted vmcnt (T4) ------
// R9: ring-3(48KB, 3 blocks/CU) -> ring-2(34KB, 4 blocks/CU).  Counters
// showed latency-bound (MFMA 30 / VALU 19 / HBM 22 / Occ 27 -- nothing
// saturated); +33% TLP is the one untouched axis in the 128^2 structure.
// [R8 evidence: 256^2 4-phase/128KB = 76.7us < ring-3's 70.6 -> that
// family is closed at K=512.]
// Ledger: step t stages t+1 into slot (t+1)&1 (last read at t-1; t-1's
// trailing barrier separates).  vmcnt(4) leaves only STAGE(t+1)'s 4 loads
// in flight => STAGE(t) has landed.  Tail: vmcnt(0).  Never 0 mid-loop.
// MFMA operands swapped (D holds C^T fragments): lane owns row m = a_,
// 4 consecutive cols n = jc*16 + q4*4 + r  -> vectorized epilogue.
// bf16 C staged through LDS (pad 136) -> 256B-contiguous coalesced stores.
template <int RELU, int RES, int OUTF, int OUTB, int SCQ, int KT>
__global__ __launch_bounds__(256, 4) void gemm_bf16(
    const __bf16* __restrict__ A, const __bf16* __restrict__ Bt,
    const float* __restrict__ bias, const float* __restrict__ Rsd,
    float* __restrict__ Cf, __bf16* __restrict__ Cb, int N, int lda, int Nt) {
  // ring: A[2][128][32] at [0,8192), B[2][128][32] at [8192,16384) elems;
  // Cs epilogue overlay 128x136 = 17408 elems (34 KB) -> LDS = 34 KB.
  __shared__ __align__(16) __bf16 smem[17408];
  int tid = threadIdx.x;
  int lane = tid & 63, w = tid >> 6;
  // XCD-aware swizzle: xcd owns a contiguous m-range (= contiguous batches)
  int Mt8 = (int)(gridDim.x / Nt) >> 3;       // m-tiles per XCD range
  int xcd = blockIdx.x & 7;
  int j = blockIdx.x >> 3;
  int rr = j % (2 * Nt), chunk = j / (2 * Nt);
  int mt = xcd * Mt8 + chunk * 2 + (rr & 1);
  int nt = rr >> 1;
  int m0 = mt * 128, n0 = nt * 128;
  int q4 = lane >> 4, a_ = lane & 15;
  const int ldb = KT * 32;
  // staging geometry: 512 16B-chunks per operand per K-step, 2 per thread.
  // chunk ci -> row = ci>>2, lds col-chunk c = ci&3 holds global chunk
  // q = c ^ ((row>>1)&3)  (involution; read applies the same XOR).
  int r0s = tid >> 2, q0s = (tid & 3) ^ ((r0s >> 1) & 3);
  int r1s = 64 + (tid >> 2), q1s = (tid & 3) ^ ((r1s >> 1) & 3);
  const __bf16* Ag = A + (size_t)m0 * lda;
  const __bf16* Bg = Bt + (size_t)n0 * ldb;

  floatx4 acc[4][4];
#pragma unroll
  for (int i = 0; i < 4; ++i)
#pragma unroll
    for (int jj = 0; jj < 4; ++jj) acc[i][jj] = (floatx4)(0.0f);

  auto STAGE = [&](int kt, int bs) {
    __bf16* Ad = smem + bs * 4096;
    __bf16* Bd = smem + 8192 + bs * 4096;
    int k0 = kt * 32;
    load16_lds(Ag + (size_t)r0s * lda + k0 + q0s * 8, Ad + tid * 8);
    load16_lds(Ag + (size_t)r1s * lda + k0 + q1s * 8, Ad + (256 + tid) * 8);
    load16_lds(Bg + (size_t)r0s * ldb + k0 + q0s * 8, Bd + tid * 8);
    load16_lds(Bg + (size_t)r1s * ldb + k0 + q1s * 8, Bd + (256 + tid) * 8);
  };

  STAGE(0, 0);
#pragma unroll
  for (int kt = 0; kt < KT; ++kt) {
    if (kt + 1 < KT) {
      STAGE(kt + 1, (kt + 1) & 1);
      asm volatile("s_waitcnt vmcnt(4)" ::: "memory");
    } else {
      asm volatile("s_waitcnt vmcnt(0)" ::: "memory");
    }
    __builtin_amdgcn_s_barrier();
    __builtin_amdgcn_sched_barrier(0);
    const __bf16* As = smem + (kt & 1) * 4096;
    const __bf16* Bs = smem + 8192 + (kt & 1) * 4096;
    bf16x8 af[4], bfr[4];
#pragma unroll
    for (int i = 0; i < 4; ++i) {
      int row = (w & 1) * 64 + i * 16 + a_;
      int pc = q4 ^ ((row >> 1) & 3);
      af[i] = *(const bf16x8*)&As[(row * 4 + pc) * 8];
    }
#pragma unroll
    for (int jc = 0; jc < 4; ++jc) {
      int row = (w >> 1) * 64 + jc * 16 + a_;
      int pc = q4 ^ ((row >> 1) & 3);
      bfr[jc] = *(const bf16x8*)&Bs[(row * 4 + pc) * 8];
    }
#pragma unroll
    for (int i = 0; i < 4; ++i)
#pragma unroll
      for (int jc = 0; jc < 4; ++jc)
        acc[i][jc] = __builtin_amdgcn_mfma_f32_16x16x32_bf16(bfr[jc], af[i],
                                                             acc[i][jc], 0, 0, 0);
    asm volatile("" ::: "memory");
    __builtin_amdgcn_s_barrier();
  }
  // ---- epilogue: vectorized, bf16 staged via LDS ----
#pragma unroll
  for (int i = 0; i < 4; ++i) {
    int ml = (w & 1) * 64 + i * 16 + a_;
    int m = m0 + ml;
#pragma unroll
    for (int jc = 0; jc < 4; ++jc) {
      int nl = (w >> 1) * 64 + jc * 16 + q4 * 4;
      int n = n0 + nl;
      float4 bi = *(const float4*)(bias + n);
      floatx4 v = acc[i][jc];
      v[0] += bi.x; v[1] += bi.y; v[2] += bi.z; v[3] += bi.w;
      if (SCQ) { if (n < 512) v *= SCALE_; }
      if (RES) {
        float4 rv = *(const float4*)(Rsd + (size_t)m * N + n);
        v[0] += rv.x; v[1] += rv.y; v[2] += rv.z; v[3] += rv.w;
      }
      if (RELU) {
#pragma unroll
        for (int r = 0; r < 4; ++r) v[r] = fmaxf(v[r], 0.f);
      }
      if (OUTF) {
        float4 o = make_float4(v[0], v[1], v[2], v[3]);
        *(float4*)(Cf + (size_t)m * N + n) = o;
      }
      if (OUTB) {
        bf16x4 ob;
#pragma unroll
        for (int r = 0; r < 4; ++r) ob[r] = (__bf16)v[r];
        *(bf16x4*)&smem[ml * 136 + nl] = ob;
      }
    }
  }
  if (OUTB) {
    __syncthreads();
#pragma unroll
    for (int it = 0; it < 8; ++it) {
      int cid = it * 256 + tid;
      int row = cid >> 4, c8 = cid & 15;
      bf16x8 val = *(const bf16x8*)&smem[row * 136 + c8 * 8];
      *(bf16x8*)(Cb + (size_t)(m0 + row) * N + n0 + c8 * 8) = val;
    }
  }
}

// ---------------- MFMA flash attention v2 (S^T layout, swizzled LDS) ------
// (R7 config: producer-aligned XCD decode; FETCH 82->49MB.  Occupancy must
// stay 2 blocks/CU -- R1/R3: more blocks collapses the L2 equilibrium.)
// R9: + s_setprio(1/0) around MFMA clusters -- m191's proven regime
// (independent blocks at different phases; GEMM-lockstep was the null case).
__global__ __launch_bounds__(256, 2) void attn_bf16(__bf16* __restrict__ QKV) {
  __shared__ __align__(16) __bf16 Qs[256 * 64];  // swizzled chunks
  __shared__ __align__(16) __bf16 Ks[64 * 64];   // swizzled
  __shared__ __align__(16) __bf16 Vt[64 * 64];   // V^T [d][t], swizzled
  __shared__ __align__(16) __bf16 Ps[64 * 64];   // P [s][t], swizzled
  int tid = threadIdx.x, lane = tid & 63, w = tid >> 6;
  int q4 = lane >> 4, a_ = lane & 15;
  int bid = blockIdx.x;
  int xg = bid & 7, slot = bid >> 3;
  int b = xg * 8 + (slot >> 4);
  int r_ = slot & 15;
  int h = r_ >> 1;
  int s0 = (r_ & 1) * 256;
  size_t rowbase = (size_t)b * S_ * QS_ + h * 64;
  __bf16* Qg = QKV + rowbase;
  const __bf16* Kg = QKV + rowbase + 512;
  const __bf16* Vg = QKV + rowbase + 1024;
  // stage Q slab (256 rows), swizzled
#pragma unroll
  for (int j = 0; j < 8; ++j) {
    int ci = j * 256 + w * 64 + lane;
    int row = ci >> 3, c = ci & 7, q = c ^ (row & 7);
    load16_lds(Qg + (size_t)(s0 + row) * QS_ + q * 8, Qs + (j * 256 + w * 64) * 8);
  }
  float mrow[4], lrow[4];
  floatx4 accO[4][4];
#pragma unroll
  for (int cc = 0; cc < 4; ++cc) {
    mrow[cc] = -3.0e38f; lrow[cc] = 0.f;
#pragma unroll
    for (int jc = 0; jc < 4; ++jc) accO[cc][jc] = (floatx4)(0.0f);
  }

  for (int t0 = 0; t0 < S_; t0 += 64) {
    // stage K tile, swizzled
#pragma unroll
    for (int j = 0; j < 2; ++j) {
      int ci = j * 256 + w * 64 + lane;
      int row = ci >> 3, c = ci & 7, q = c ^ (row & 7);
      load16_lds(Kg + (size_t)(t0 + row) * QS_ + q * 8, Ks + (j * 256 + w * 64) * 8);
    }
    // stage V transposed -> Vt[d][t], swizzled chunks
    {
      int tp = tid & 31, dg = tid >> 5;
      bf16x8 v0 = *(const bf16x8*)(Vg + (size_t)(t0 + 2 * tp) * QS_ + dg * 8);
      bf16x8 v1 = *(const bf16x8*)(Vg + (size_t)(t0 + 2 * tp + 1) * QS_ + dg * 8);
#pragma unroll
      for (int x = 0; x < 8; ++x) {
        int d = dg * 8 + x;
        bf16x2 p; p[0] = v0[x]; p[1] = v1[x];
        *(bf16x2*)&Vt[(d * 8 + ((tp >> 2) ^ (d & 7))) * 8 + (tp & 3) * 2] = p;
      }
    }
    __syncthreads();
    // K and V^T fragments (shared across the 4 s-chunks)
    bf16x8 af[2][4], bv[2][4];
#pragma unroll
    for (int ks = 0; ks < 2; ++ks)
#pragma unroll
      for (int jc = 0; jc < 4; ++jc) {
        int row = jc * 16 + a_, q = ks * 4 + q4;
        af[ks][jc] = *(const bf16x8*)&Ks[(row * 8 + (q ^ (row & 7))) * 8];
        bv[ks][jc] = *(const bf16x8*)&Vt[(row * 8 + (q ^ (row & 7))) * 8];
      }
#pragma unroll
    for (int cc = 0; cc < 4; ++cc) {
      int sbase = (cc * 4 + w) * 16;
      // S^T = K Q^T : rows t = jc*16+q4*4+r, col s = sbase + a_
      floatx4 sc[4];
#pragma unroll
      for (int jc = 0; jc < 4; ++jc) sc[jc] = (floatx4)(0.0f);
      __builtin_amdgcn_s_setprio(1);
#pragma unroll
      for (int ks = 0; ks < 2; ++ks) {
        int row = sbase + a_, q = ks * 4 + q4;
        bf16x8 bq = *(const bf16x8*)&Qs[(row * 8 + (q ^ (row & 7))) * 8];
#pragma unroll
        for (int jc = 0; jc < 4; ++jc)
          sc[jc] = __builtin_amdgcn_mfma_f32_16x16x32_bf16(af[ks][jc], bq,
                                                           sc[jc], 0, 0, 0);
      }
      __builtin_amdgcn_s_setprio(0);
      // online softmax: per lane, all 16 values share column s = sbase+a_
      float mx = sc[0][0];
#pragma unroll
      for (int jc = 0; jc < 4; ++jc)
#pragma unroll
        for (int r = 0; r < 4; ++r) mx = fmaxf(mx, sc[jc][r]);
      mx = fmaxf(mx, __shfl_xor(mx, 16));
      mx = fmaxf(mx, __shfl_xor(mx, 32));
      float mnew = fmaxf(mrow[cc], mx);
      float alpha = __expf(mrow[cc] - mnew);
      mrow[cc] = mnew;
      float ps = 0.f;
      int prow = w * 16 + a_;
#pragma unroll
      for (int jc = 0; jc < 4; ++jc) {
        bf16x4 pb;
#pragma unroll
        for (int r = 0; r < 4; ++r) {
          float p = __expf(sc[jc][r] - mnew);
          ps += p;
          pb[r] = (__bf16)p;
        }
        int pc = jc * 2 + (q4 >> 1);
        *(bf16x4*)&Ps[(prow * 8 + (pc ^ (prow & 7))) * 8 + (q4 & 1) * 4] = pb;
      }
      ps += __shfl_xor(ps, 16);
      ps += __shfl_xor(ps, 32);
      lrow[cc] = lrow[cc] * alpha + ps;
      float aal[4];
#pragma unroll
      for (int r = 0; r < 4; ++r) aal[r] = __shfl(alpha, q4 * 4 + r);
#pragma unroll
      for (int jc = 0; jc < 4; ++jc) {
        floatx4 t = accO[cc][jc];
#pragma unroll
        for (int r = 0; r < 4; ++r) t[r] *= aal[r];
        accO[cc][jc] = t;
      }
      // O += P V  (Ps rows wave-private; same-wave LDS RAW ordered via lgkmcnt)
      __builtin_amdgcn_s_setprio(1);
#pragma unroll
      for (int ks = 0; ks < 2; ++ks) {
        int q = ks * 4 + q4;
        bf16x8 ap = *(const bf16x8*)&Ps[(prow * 8 + (q ^ (prow & 7))) * 8];
#pragma unroll
        for (int jc = 0; jc < 4; ++jc)
          accO[cc][jc] = __builtin_amdgcn_mfma_f32_16x16x32_bf16(
              ap, bv[ks][jc], accO[cc][jc], 0, 0, 0);
      }
      __builtin_amdgcn_s_setprio(0);
    }
    __syncthreads();
  }
  // epilogue: row = s0+(cc*4+w)*16+q4*4+r, col = jc*16+a_  (into Q slice)
#pragma unroll
  for (int cc = 0; cc < 4; ++cc) {
    float inv = 1.f / lrow[cc];
    float linv[4];
#pragma unroll
    for (int r = 0; r < 4; ++r) linv[r] = __shfl(inv, q4 * 4 + r);
    int srow = s0 + (cc * 4 + w) * 16 + q4 * 4;
#pragma unroll
    for (int r = 0; r < 4; ++r)
#pragma unroll
      for (int jc = 0; jc < 4; ++jc)
        Qg[(size_t)(srow + r) * QS_ + jc * 16 + a_] =
            (__bf16)(accO[cc][jc][r] * linv[r]);
  }
}

// ---------------- add + l2norm: X = l2norm(X + MH), Ab = bf16(X) ----------
__global__ __launch_bounds__(256) void addnorm_kernel(
    float* __restrict__ X, const __bf16* __restrict__ MH, __bf16* __restrict__ Ab) {
  int row = blockIdx.x * 4 + (threadIdx.x >> 6);
  int ln = threadIdx.x & 63;
  size_t off = (size_t)row * E_ + ln * 8;
  float xv[8];
  *(float4*)&xv[0] = *(const float4*)(X + off);
  *(float4*)&xv[4] = *(const float4*)(X + off + 4);
  bf16x8 mh = *(const bf16x8*)(MH + off);
  float ss = 0.f;
#pragma unroll
  for (int j = 0; j < 8; ++j) {
    xv[j] += (float)mh[j];
    ss += xv[j] * xv[j];
  }
#pragma unroll
  for (int o = 1; o < 64; o <<= 1) ss += __shfl_xor(ss, o);
  float inv = rsqrtf(fmaxf(ss, 1e-12f));
  bf16x8 ob;
#pragma unroll
  for (int j = 0; j < 8; ++j) {
    xv[j] *= inv;
    ob[j] = (__bf16)xv[j];
  }
  *(float4*)(X + off) = *(float4*)&xv[0];
  *(float4*)(X + off + 4) = *(float4*)&xv[4];
  *(bf16x8*)(Ab + off) = ob;
}

// ---------------- conv-pool: pooled[b][l] = dot(X[b, 5l:5l+5, :], Wc)+bc ---
__global__ __launch_bounds__(256) void conv_pool_kernel(
    const float* __restrict__ X, const float* __restrict__ Wc,
    const float* __restrict__ bc, float* __restrict__ pooled) {
  int wid = blockIdx.x * 4 + (threadIdx.x >> 6);
  int ln = threadIdx.x & 63;
  int b = wid / LOUT_, l = wid % LOUT_;
  const float* xr = X + (size_t)b * S_ * E_ + (size_t)l * 5 * E_;
  float v = 0.f;
#pragma unroll
  for (int j = 0; j < 10; ++j) {
    int i = (j * 64 + ln) * 4;
    float4 x4 = *(const float4*)(xr + i);
    float4 w4 = *(const float4*)(Wc + i);
    v += x4.x * w4.x + x4.y * w4.y + x4.z * w4.z + x4.w * w4.w;
  }
#pragma unroll
  for (int o = 32; o >= 1; o >>= 1) v += __shfl_down(v, o);
  if (ln == 0) pooled[b * LOUT_ + l] = v + bc[0];
}

// ---------------- dense + softmax: out[b] = softmax(pooled[b] @ Wd + bd) ---
__global__ __launch_bounds__(256) void dense_softmax_kernel(
    const float* __restrict__ pooled, const float* __restrict__ Wd,
    const float* __restrict__ bd, float* __restrict__ out) {
  __shared__ float pl[LOUT_];
  __shared__ float red[256];
  __shared__ float lg[O_];
  int b = blockIdx.x, tid = threadIdx.x;
  if (tid < LOUT_) pl[tid] = pooled[b * LOUT_ + tid];
  __syncthreads();
  for (int o = tid; o < O_; o += 256) {
    float acc = bd[o];
#pragma unroll 6
    for (int l = 0; l < LOUT_; ++l) acc += pl[l] * Wd[l * O_ + o];
    lg[o] = acc;
  }
  __syncthreads();
  float mx = -3.0e38f;
  for (int o = tid; o < O_; o += 256) mx = fmaxf(mx, lg[o]);
  red[tid] = mx;
  __syncthreads();
  for (int s2 = 128; s2 > 0; s2 >>= 1) {
    if (tid < s2) red[tid] = fmaxf(red[tid], red[tid + s2]);
    __syncthreads();
  }
  mx = red[0];
  __syncthreads();
  float se = 0.f;
  for (int o = tid; o < O_; o += 256) {
    float e = __expf(lg[o] - mx);
    lg[o] = e;
    se += e;
  }
  red[tid] = se;
  __syncthreads();
  for (int s2 = 128; s2 > 0; s2 >>= 1) {
    if (tid < s2) red[tid] += red[tid + s2];
    __syncthreads();
  }
  float inv = 1.f / red[0];
  for (int o = tid; o < O_; o += 256) out[(size_t)b * O_ + o] = lg[o] * inv;
}

extern "C" void kernel_launch(void* const* d_in, const int* in_sizes, int n_in,
                              void* d_out, int out_size, void* d_ws, size_t ws_size,
                              hipStream_t stream) {
  const int* tokens = (const int*)d_in[0];
  const float* emb = (const float*)d_in[1];
  const float* Wq = (const float*)d_in[2];
  const float* bq = (const float*)d_in[3];
  const float* Wk = (const float*)d_in[4];
  const float* bk = (const float*)d_in[5];
  const float* Wv = (const float*)d_in[6];
  const float* bv = (const float*)d_in[7];
  const float* Wo = (const float*)d_in[8];
  const float* bo = (const float*)d_in[9];
  const float* W1 = (const float*)d_in[10];
  const float* b1 = (const float*)d_in[11];
  const float* W2 = (const float*)d_in[12];
  const float* b2 = (const float*)d_in[13];
  const float* Wc = (const float*)d_in[14];
  const float* bc = (const float*)d_in[15];
  const float* Wd = (const float*)d_in[16];
  const float* bd = (const float*)d_in[17];
  float* out = (float*)d_out;

  // ws layout (bytes): X f32 [0,64M) | Ab bf16 [64M,96M) | QKVb [96M,192M)
  // | MH [192M,224M) | Wt [224M,240M) | qkvbias/pooled [240M,...)
  char* ws = (char*)d_ws;
  float* X = (float*)ws;
  __bf16* Ab = (__bf16*)(ws + 67108864);
  __bf16* QKVb = (__bf16*)(ws + 100663296);
  __bf16* FF1b = QKVb;  // reuse (QKV dead after Wo gemm)
  __bf16* MHb = (__bf16*)(ws + 201326592);
  __bf16* Wt = (__bf16*)(ws + 234881024);
  __bf16* Wt_qkv = Wt;                 // [L][1536][512]
  __bf16* Wt_o = Wt + 3145728;         // [L][512][512]
  __bf16* Wt_1 = Wt + 4194304;         // [L][1024][512]
  __bf16* Wt_2 = Wt + 6291456;         // [L][512][1024]
  float* qkvbias = (float*)(ws + 251658240);
  float* pooled = qkvbias + 6144;

  dim3 tb(32, 8);
  transpose_bf16<<<dim3(2, 16, 32), tb, 0, stream>>>(Wq, Wt_qkv + 0,      512, 64, 32768, 786432, 32768);
  transpose_bf16<<<dim3(2, 16, 32), tb, 0, stream>>>(Wk, Wt_qkv + 262144, 512, 64, 32768, 786432, 32768);
  transpose_bf16<<<dim3(2, 16, 32), tb, 0, stream>>>(Wv, Wt_qkv + 524288, 512, 64, 32768, 786432, 32768);
  transpose_bf16<<<dim3(16, 16, 4), tb, 0, stream>>>(Wo, Wt_o, 512, 512, 262144, 0, 262144);
  transpose_bf16<<<dim3(32, 16, 4), tb, 0, stream>>>(W1, Wt_1, 512, 1024, 524288, 0, 524288);
  transpose_bf16<<<dim3(16, 32, 4), tb, 0, stream>>>(W2, Wt_2, 1024, 512, 524288, 0, 524288);
  bias_concat<<<dim3(24), dim3(256), 0, stream>>>(bq, bk, bv, qkvbias);

  embed_kernel<<<dim3(BS_ * E_ / 4 / 256), dim3(256), 0, stream>>>(tokens, emb, X, Ab);

  dim3 blk(256);
  for (int i = 0; i < L_; ++i) {
    gemm_bf16<0, 0, 0, 1, 1, 16><<<dim3(256 * 12), blk, 0, stream>>>(
        Ab, Wt_qkv + (size_t)i * 786432, qkvbias + i * QS_, nullptr, nullptr,
        QKVb, QS_, 512, 12);
    attn_bf16<<<dim3(1024), blk, 0, stream>>>(QKVb);
    gemm_bf16<0, 0, 0, 1, 0, 16><<<dim3(256 * 4), blk, 0, stream>>>(
        QKVb, Wt_o + (size_t)i * 262144, bo + i * E_, nullptr, nullptr, MHb,
        512, QS_, 4);
    addnorm_kernel<<<dim3(BS_ / 4), blk, 0, stream>>>(X, MHb, Ab);
    gemm_bf16<1, 0, 0, 1, 0, 16><<<dim3(256 * 8), blk, 0, stream>>>(
        Ab, Wt_1 + (size_t)i * 524288, b1 + (size_t)i * 2 * E_, nullptr, nullptr,
        FF1b, 1024, 512, 8);
    gemm_bf16<0, 1, 1, 1, 0, 32><<<dim3(256 * 4), blk, 0, stream>>>(
        FF1b, Wt_2 + (size_t)i * 524288, b2 + (size_t)i * E_, X, X, Ab,
        512, 1024, 4);
  }
  conv_pool_kernel<<<dim3(BS_ * LOUT_ / S_ / 4), blk, 0, stream>>>(X, Wc, bc, pooled);
  dense_softmax_kernel<<<dim3(B_), blk, 0, stream>>>(pooled, Wd, bd, out);
}

// Round 10
// 1390.605 us; speedup vs baseline: 1.0323x; 1.0323x over previous
//
#include <hip/hip_runtime.h>
#include <cstddef>

constexpr int B_ = 64, S_ = 512, E_ = 512, H_ = 8, D_ = 64, L_ = 4, O_ = 1000;
constexpr int BS_ = B_ * S_;        // 32768
constexpr int HD_ = H_ * D_;        // 512
constexpr int QS_ = 1536;           // fused QKV row stride
constexpr int LOUT_ = 102;
constexpr float SCALE_ = 0.04419417382415922f;  // 1/sqrt(512)

typedef __bf16 bf16x8 __attribute__((ext_vector_type(8)));
typedef __bf16 bf16x4 __attribute__((ext_vector_type(4)));
typedef __bf16 bf16x2 __attribute__((ext_vector_type(2)));
typedef float floatx4 __attribute__((ext_vector_type(4)));

__device__ inline void load16_lds(const __bf16* g, __bf16* l) {
  __builtin_amdgcn_global_load_lds(
      (const __attribute__((address_space(1))) void*)g,
      (__attribute__((address_space(3))) void*)l, 16, 0, 0);
}

// ---------------- weight transpose + bf16 convert ----------------
__global__ __launch_bounds__(256) void transpose_bf16(
    const float* __restrict__ in, __bf16* __restrict__ out,
    int R, int C, int IZ, int OZL, int OZH) {
  __shared__ float t[32][33];
  int z = blockIdx.z;
  const float* inz = in + (size_t)z * IZ;
  __bf16* outz = out + (size_t)(z >> 3) * OZL + (size_t)(z & 7) * OZH;
  int c0 = blockIdx.x * 32, r0 = blockIdx.y * 32;
  int x = threadIdx.x, y = threadIdx.y;  // (32,8)
#pragma unroll
  for (int j = 0; j < 32; j += 8) t[y + j][x] = inz[(size_t)(r0 + y + j) * C + c0 + x];
  __syncthreads();
#pragma unroll
  for (int j = 0; j < 32; j += 8)
    outz[(size_t)(c0 + y + j) * R + r0 + x] = (__bf16)t[x][y + j];
}

// ---------------- concat qkv bias: [L][1536] = bq|bk|bv ----------------
__global__ __launch_bounds__(256) void bias_concat(
    const float* __restrict__ bq, const float* __restrict__ bk,
    const float* __restrict__ bv, float* __restrict__ qkvb) {
  int idx = blockIdx.x * 256 + threadIdx.x;  // < 6144
  int l = idx / QS_, j = idx % QS_;
  float v;
  if (j < 512) v = bq[l * 512 + j];
  else if (j < 1024) v = bk[l * 512 + j - 512];
  else v = bv[l * 512 + j - 1024];
  qkvb[idx] = v;
}

// ---------------- embedding + mask -> X fp32 + Ab bf16 ----------------
__global__ __launch_bounds__(256) void embed_kernel(
    const int* __restrict__ tokens, const float* __restrict__ emb,
    float* __restrict__ X, __bf16* __restrict__ Ab) {
  int idx = blockIdx.x * 256 + threadIdx.x;  // float4 index
  int bs = idx >> 7;
  int e = (idx & 127) << 2;
  int tok = tokens[bs];
  float4 v;
  if (tok == 0) v = make_float4(0.f, 0.f, 0.f, 0.f);
  else v = *(const float4*)(emb + (size_t)tok * E_ + e);
  size_t off = (size_t)bs * E_ + e;
  *(float4*)(X + off) = v;
  bf16x4 b;
  b[0] = (__bf16)v.x; b[1] = (__bf16)v.y; b[2] = (__bf16)v.z; b[3] = (__bf16)v.w;
  *(bf16x4*)(Ab + off) = b;
}

// ---------------- bf16 MFMA GEMM, ring-3 LDS + counted vmcnt (T4) ------
// (R7-proven config: 70.6us QKV, best total 1390.  Closed probes: setprio
// negative [R4], 256^2 coarse & 4-phase negative [R6/R8], ring-2 4blk
// neutral-negative [R9].  This is the config of record.)
// Ledger: iter kt stages buf[(kt+2)%3] (last read at kt-1, next read kt+2;
// a barrier separates every read-set from the overwriting issue).
// vmcnt(8) leaves the 2 newer K-steps (4 loads each) in flight => step kt
// has landed.  Tail: 8 -> 4 -> 0.  Never 0 mid-loop.
template <int RELU, int RES, int OUTF, int OUTB, int SCQ, int KT>
__global__ __launch_bounds__(256) void gemm_bf16(
    const __bf16* __restrict__ A, const __bf16* __restrict__ Bt,
    const float* __restrict__ bias, const float* __restrict__ Rsd,
    float* __restrict__ Cf, __bf16* __restrict__ Cb, int N, int lda, int Nt) {
  // ring: A[3][128][32] at [0,12288), B[3][128][32] at [12288,24576); Cs overlay
  __shared__ __align__(16) __bf16 smem[24576];  // 48 KB
  int tid = threadIdx.x;
  int lane = tid & 63, w = tid >> 6;
  // XCD-aware swizzle: xcd owns a contiguous m-range (= contiguous batches)
  int Mt8 = (int)(gridDim.x / Nt) >> 3;       // m-tiles per XCD range
  int xcd = blockIdx.x & 7;
  int j = blockIdx.x >> 3;
  int rr = j % (2 * Nt), chunk = j / (2 * Nt);
  int mt = xcd * Mt8 + chunk * 2 + (rr & 1);
  int nt = rr >> 1;
  int m0 = mt * 128, n0 = nt * 128;
  int q4 = lane >> 4, a_ = lane & 15;
  const int ldb = KT * 32;
  int r0s = tid >> 2, q0s = (tid & 3) ^ ((r0s >> 1) & 3);
  int r1s = 64 + (tid >> 2), q1s = (tid & 3) ^ ((r1s >> 1) & 3);
  const __bf16* Ag = A + (size_t)m0 * lda;
  const __bf16* Bg = Bt + (size_t)n0 * ldb;

  floatx4 acc[4][4];
#pragma unroll
  for (int i = 0; i < 4; ++i)
#pragma unroll
    for (int jj = 0; jj < 4; ++jj) acc[i][jj] = (floatx4)(0.0f);

  auto STAGE = [&](int kt, int bs) {
    __bf16* Ad = smem + bs * 4096;
    __bf16* Bd = smem + 12288 + bs * 4096;
    int k0 = kt * 32;
    load16_lds(Ag + (size_t)r0s * lda + k0 + q0s * 8, Ad + tid * 8);
    load16_lds(Ag + (size_t)r1s * lda + k0 + q1s * 8, Ad + (256 + tid) * 8);
    load16_lds(Bg + (size_t)r0s * ldb + k0 + q0s * 8, Bd + tid * 8);
    load16_lds(Bg + (size_t)r1s * ldb + k0 + q1s * 8, Bd + (256 + tid) * 8);
  };

  STAGE(0, 0);
  if (KT > 1) STAGE(1, 1);
#pragma unroll
  for (int kt = 0; kt < KT; ++kt) {
    if (kt + 2 < KT) {
      STAGE(kt + 2, (kt + 2) % 3);
      asm volatile("s_waitcnt vmcnt(8)" ::: "memory");
    } else if (kt + 1 < KT) {
      asm volatile("s_waitcnt vmcnt(4)" ::: "memory");
    } else {
      asm volatile("s_waitcnt vmcnt(0)" ::: "memory");
    }
    __builtin_amdgcn_s_barrier();
    __builtin_amdgcn_sched_barrier(0);
    const __bf16* As = smem + (kt % 3) * 4096;
    const __bf16* Bs = smem + 12288 + (kt % 3) * 4096;
    bf16x8 af[4], bfr[4];
#pragma unroll
    for (int i = 0; i < 4; ++i) {
      int row = (w & 1) * 64 + i * 16 + a_;
      int pc = q4 ^ ((row >> 1) & 3);
      af[i] = *(const bf16x8*)&As[(row * 4 + pc) * 8];
    }
#pragma unroll
    for (int jc = 0; jc < 4; ++jc) {
      int row = (w >> 1) * 64 + jc * 16 + a_;
      int pc = q4 ^ ((row >> 1) & 3);
      bfr[jc] = *(const bf16x8*)&Bs[(row * 4 + pc) * 8];
    }
#pragma unroll
    for (int i = 0; i < 4; ++i)
#pragma unroll
      for (int jc = 0; jc < 4; ++jc)
        acc[i][jc] = __builtin_amdgcn_mfma_f32_16x16x32_bf16(bfr[jc], af[i],
                                                             acc[i][jc], 0, 0, 0);
    asm volatile("" ::: "memory");
    __builtin_amdgcn_s_barrier();
  }
  // ---- epilogue: vectorized, bf16 staged via LDS ----
#pragma unroll
  for (int i = 0; i < 4; ++i) {
    int ml = (w & 1) * 64 + i * 16 + a_;
    int m = m0 + ml;
#pragma unroll
    for (int jc = 0; jc < 4; ++jc) {
      int nl = (w >> 1) * 64 + jc * 16 + q4 * 4;
      int n = n0 + nl;
      float4 bi = *(const float4*)(bias + n);
      floatx4 v = acc[i][jc];
      v[0] += bi.x; v[1] += bi.y; v[2] += bi.z; v[3] += bi.w;
      if (SCQ) { if (n < 512) v *= SCALE_; }
      if (RES) {
        float4 rv = *(const float4*)(Rsd + (size_t)m * N + n);
        v[0] += rv.x; v[1] += rv.y; v[2] += rv.z; v[3] += rv.w;
      }
      if (RELU) {
#pragma unroll
        for (int r = 0; r < 4; ++r) v[r] = fmaxf(v[r], 0.f);
      }
      if (OUTF) {
        float4 o = make_float4(v[0], v[1], v[2], v[3]);
        *(float4*)(Cf + (size_t)m * N + n) = o;
      }
      if (OUTB) {
        bf16x4 ob;
#pragma unroll
        for (int r = 0; r < 4; ++r) ob[r] = (__bf16)v[r];
        *(bf16x4*)&smem[ml * 136 + nl] = ob;
      }
    }
  }
  if (OUTB) {
    __syncthreads();
#pragma unroll
    for (int it = 0; it < 8; ++it) {
      int cid = it * 256 + tid;
      int row = cid >> 4, c8 = cid & 15;
      bf16x8 val = *(const bf16x8*)&smem[row * 136 + c8 * 8];
      *(bf16x8*)(Cb + (size_t)(m0 + row) * N + n0 + c8 * 8) = val;
    }
  }
}

// ---------------- MFMA flash attention v2 (S^T layout, swizzled LDS) ------
// R10: K/V DOUBLE-BUFFER + T14 split.  The old loop drained vmcnt to 0 at
// every 64-row tile via __syncthreads with only 2 blocks/CU to cover it.
// Now: K(t+1) gload_lds issued before the barrier stays in flight across it
// (vmcnt(2)); V(t+1) issued as reg-loads early, ds_written late next iter.
// LDS 72KB (Qs32+K16+V16+Ps8) -> still 2 blocks/CU: the R1/R3 L2
// equilibrium is untouched.  setprio removed (R9: -8.7us, lockstep waves).
// Ledger (per-wave FIFO): [Q(8)], K(t):2, V(t):2, K(t+1):2.
//  iter t: issue K(t+1)->buf cur^1 (last read t-1, trailing barrier since);
//  vmcnt(2) completes K(t)+V(t) [iter0: +Q]; ds_write V(t)->Vt[cur];
//  issue V(t+1) reg-loads; lgkmcnt(0)+barrier (Vt visible); compute cur;
//  trailing barrier (protects cur from K(t+2) overwrite).  Tail: vmcnt(0).
__global__ __launch_bounds__(256, 2) void attn_bf16(__bf16* __restrict__ QKV) {
  __shared__ __align__(16) __bf16 Qs[256 * 64];   // swizzled chunks
  __shared__ __align__(16) __bf16 Ks[2][64 * 64]; // swizzled, dbuf
  __shared__ __align__(16) __bf16 Vt[2][64 * 64]; // V^T [d][t], swizzled, dbuf
  __shared__ __align__(16) __bf16 Ps[64 * 64];    // P [s][t], swizzled
  int tid = threadIdx.x, lane = tid & 63, w = tid >> 6;
  int q4 = lane >> 4, a_ = lane & 15;
  int bid = blockIdx.x;
  int xg = bid & 7, slot = bid >> 3;
  int b = xg * 8 + (slot >> 4);           // producer-aligned XCD decode (R7)
  int r_ = slot & 15;
  int h = r_ >> 1;
  int s0 = (r_ & 1) * 256;
  size_t rowbase = (size_t)b * S_ * QS_ + h * 64;
  __bf16* Qg = QKV + rowbase;
  const __bf16* Kg = QKV + rowbase + 512;
  const __bf16* Vg = QKV + rowbase + 1024;
  // stage Q slab (256 rows), swizzled (8 gload_lds -> vmcnt FIFO head)
#pragma unroll
  for (int j = 0; j < 8; ++j) {
    int ci = j * 256 + w * 64 + lane;
    int row = ci >> 3, c = ci & 7, q = c ^ (row & 7);
    load16_lds(Qg + (size_t)(s0 + row) * QS_ + q * 8, Qs + (j * 256 + w * 64) * 8);
  }
  // prologue: K(0) -> Ks[0]; V(0) -> regs
#pragma unroll
  for (int j = 0; j < 2; ++j) {
    int ci = j * 256 + w * 64 + lane;
    int row = ci >> 3, c = ci & 7, q = c ^ (row & 7);
    load16_lds(Kg + (size_t)row * QS_ + q * 8, &Ks[0][(j * 256 + w * 64) * 8]);
  }
  int tp = tid & 31, dg = tid >> 5;
  bf16x8 v0 = *(const bf16x8*)(Vg + (size_t)(2 * tp) * QS_ + dg * 8);
  bf16x8 v1 = *(const bf16x8*)(Vg + (size_t)(2 * tp + 1) * QS_ + dg * 8);

  float mrow[4], lrow[4];
  floatx4 accO[4][4];
#pragma unroll
  for (int cc = 0; cc < 4; ++cc) {
    mrow[cc] = -3.0e38f; lrow[cc] = 0.f;
#pragma unroll
    for (int jc = 0; jc < 4; ++jc) accO[cc][jc] = (floatx4)(0.0f);
  }

  for (int t = 0; t < 8; ++t) {
    int t0 = t * 64;
    int cur = t & 1;
    if (t + 1 < 8) {
      // issue K(t+1) -> Ks[cur^1]; stays in flight across the barrier
#pragma unroll
      for (int j = 0; j < 2; ++j) {
        int ci = j * 256 + w * 64 + lane;
        int row = ci >> 3, c = ci & 7, q = c ^ (row & 7);
        load16_lds(Kg + (size_t)(t0 + 64 + row) * QS_ + q * 8,
                   &Ks[cur ^ 1][(j * 256 + w * 64) * 8]);
      }
      asm volatile("s_waitcnt vmcnt(2)" ::: "memory");
    } else {
      asm volatile("s_waitcnt vmcnt(0)" ::: "memory");
    }
    // write V(t) regs -> Vt[cur] (T14 write-late)
#pragma unroll
    for (int x = 0; x < 8; ++x) {
      int d = dg * 8 + x;
      bf16x2 p; p[0] = v0[x]; p[1] = v1[x];
      *(bf16x2*)&Vt[cur][(d * 8 + ((tp >> 2) ^ (d & 7))) * 8 + (tp & 3) * 2] = p;
    }
    if (t + 1 < 8) {
      // issue V(t+1) reg-loads (T14 issue-early)
      v0 = *(const bf16x8*)(Vg + (size_t)(t0 + 64 + 2 * tp) * QS_ + dg * 8);
      v1 = *(const bf16x8*)(Vg + (size_t)(t0 + 64 + 2 * tp + 1) * QS_ + dg * 8);
    }
    asm volatile("s_waitcnt lgkmcnt(0)" ::: "memory");
    __builtin_amdgcn_s_barrier();
    asm volatile("" ::: "memory");
    // K and V^T fragments from buf cur (shared across the 4 s-chunks)
    bf16x8 af[2][4], bv[2][4];
#pragma unroll
    for (int ks = 0; ks < 2; ++ks)
#pragma unroll
      for (int jc = 0; jc < 4; ++jc) {
        int row = jc * 16 + a_, q = ks * 4 + q4;
        af[ks][jc] = *(const bf16x8*)&Ks[cur][(row * 8 + (q ^ (row & 7))) * 8];
        bv[ks][jc] = *(const bf16x8*)&Vt[cur][(row * 8 + (q ^ (row & 7))) * 8];
      }
#pragma unroll
    for (int cc = 0; cc < 4; ++cc) {
      int sbase = (cc * 4 + w) * 16;
      // S^T = K Q^T : rows t = jc*16+q4*4+r, col s = sbase + a_
      floatx4 sc[4];
#pragma unroll
      for (int jc = 0; jc < 4; ++jc) sc[jc] = (floatx4)(0.0f);
#pragma unroll
      for (int ks = 0; ks < 2; ++ks) {
        int row = sbase + a_, q = ks * 4 + q4;
        bf16x8 bq = *(const bf16x8*)&Qs[(row * 8 + (q ^ (row & 7))) * 8];
#pragma unroll
        for (int jc = 0; jc < 4; ++jc)
          sc[jc] = __builtin_amdgcn_mfma_f32_16x16x32_bf16(af[ks][jc], bq,
                                                           sc[jc], 0, 0, 0);
      }
      // online softmax: per lane, all 16 values share column s = sbase+a_
      float mx = sc[0][0];
#pragma unroll
      for (int jc = 0; jc < 4; ++jc)
#pragma unroll
        for (int r = 0; r < 4; ++r) mx = fmaxf(mx, sc[jc][r]);
      mx = fmaxf(mx, __shfl_xor(mx, 16));
      mx = fmaxf(mx, __shfl_xor(mx, 32));
      float mnew = fmaxf(mrow[cc], mx);
      float alpha = __expf(mrow[cc] - mnew);
      mrow[cc] = mnew;
      float ps = 0.f;
      int prow = w * 16 + a_;
#pragma unroll
      for (int jc = 0; jc < 4; ++jc) {
        bf16x4 pb;
#pragma unroll
        for (int r = 0; r < 4; ++r) {
          float p = __expf(sc[jc][r] - mnew);
          ps += p;
          pb[r] = (__bf16)p;
        }
        int pc = jc * 2 + (q4 >> 1);
        *(bf16x4*)&Ps[(prow * 8 + (pc ^ (prow & 7))) * 8 + (q4 & 1) * 4] = pb;
      }
      ps += __shfl_xor(ps, 16);
      ps += __shfl_xor(ps, 32);
      lrow[cc] = lrow[cc] * alpha + ps;
      float aal[4];
#pragma unroll
      for (int r = 0; r < 4; ++r) aal[r] = __shfl(alpha, q4 * 4 + r);
#pragma unroll
      for (int jc = 0; jc < 4; ++jc) {
        floatx4 tt = accO[cc][jc];
#pragma unroll
        for (int r = 0; r < 4; ++r) tt[r] *= aal[r];
        accO[cc][jc] = tt;
      }
      // O += P V  (Ps rows wave-private; same-wave LDS RAW ordered via lgkmcnt)
#pragma unroll
      for (int ks = 0; ks < 2; ++ks) {
        int q = ks * 4 + q4;
        bf16x8 ap = *(const bf16x8*)&Ps[(prow * 8 + (q ^ (prow & 7))) * 8];
#pragma unroll
        for (int jc = 0; jc < 4; ++jc)
          accO[cc][jc] = __builtin_amdgcn_mfma_f32_16x16x32_bf16(
              ap, bv[ks][jc], accO[cc][jc], 0, 0, 0);
      }
    }
    asm volatile("" ::: "memory");
    __builtin_amdgcn_s_barrier();
    asm volatile("" ::: "memory");
  }
  // epilogue: row = s0+(cc*4+w)*16+q4*4+r, col = jc*16+a_  (into Q slice)
#pragma unroll
  for (int cc = 0; cc < 4; ++cc) {
    float inv = 1.f / lrow[cc];
    float linv[4];
#pragma unroll
    for (int r = 0; r < 4; ++r) linv[r] = __shfl(inv, q4 * 4 + r);
    int srow = s0 + (cc * 4 + w) * 16 + q4 * 4;
#pragma unroll
    for (int r = 0; r < 4; ++r)
#pragma unroll
      for (int jc = 0; jc < 4; ++jc)
        Qg[(size_t)(srow + r) * QS_ + jc * 16 + a_] =
            (__bf16)(accO[cc][jc][r] * linv[r]);
  }
}

// ---------------- add + l2norm: X = l2norm(X + MH), Ab = bf16(X) ----------
__global__ __launch_bounds__(256) void addnorm_kernel(
    float* __restrict__ X, const __bf16* __restrict__ MH, __bf16* __restrict__ Ab) {
  int row = blockIdx.x * 4 + (threadIdx.x >> 6);
  int ln = threadIdx.x & 63;
  size_t off = (size_t)row * E_ + ln * 8;
  float xv[8];
  *(float4*)&xv[0] = *(const float4*)(X + off);
  *(float4*)&xv[4] = *(const float4*)(X + off + 4);
  bf16x8 mh = *(const bf16x8*)(MH + off);
  float ss = 0.f;
#pragma unroll
  for (int j = 0; j < 8; ++j) {
    xv[j] += (float)mh[j];
    ss += xv[j] * xv[j];
  }
#pragma unroll
  for (int o = 1; o < 64; o <<= 1) ss += __shfl_xor(ss, o);
  float inv = rsqrtf(fmaxf(ss, 1e-12f));
  bf16x8 ob;
#pragma unroll
  for (int j = 0; j < 8; ++j) {
    xv[j] *= inv;
    ob[j] = (__bf16)xv[j];
  }
  *(float4*)(X + off) = *(float4*)&xv[0];
  *(float4*)(X + off + 4) = *(float4*)&xv[4];
  *(bf16x8*)(Ab + off) = ob;
}

// ---------------- conv-pool: pooled[b][l] = dot(X[b, 5l:5l+5, :], Wc)+bc ---
__global__ __launch_bounds__(256) void conv_pool_kernel(
    const float* __restrict__ X, const float* __restrict__ Wc,
    const float* __restrict__ bc, float* __restrict__ pooled) {
  int wid = blockIdx.x * 4 + (threadIdx.x >> 6);
  int ln = threadIdx.x & 63;
  int b = wid / LOUT_, l = wid % LOUT_;
  const float* xr = X + (size_t)b * S_ * E_ + (size_t)l * 5 * E_;
  float v = 0.f;
#pragma unroll
  for (int j = 0; j < 10; ++j) {
    int i = (j * 64 + ln) * 4;
    float4 x4 = *(const float4*)(xr + i);
    float4 w4 = *(const float4*)(Wc + i);
    v += x4.x * w4.x + x4.y * w4.y + x4.z * w4.z + x4.w * w4.w;
  }
#pragma unroll
  for (int o = 32; o >= 1; o >>= 1) v += __shfl_down(v, o);
  if (ln == 0) pooled[b * LOUT_ + l] = v + bc[0];
}

// ---------------- dense + softmax: out[b] = softmax(pooled[b] @ Wd + bd) ---
__global__ __launch_bounds__(256) void dense_softmax_kernel(
    const float* __restrict__ pooled, const float* __restrict__ Wd,
    const float* __restrict__ bd, float* __restrict__ out) {
  __shared__ float pl[LOUT_];
  __shared__ float red[256];
  __shared__ float lg[O_];
  int b = blockIdx.x, tid = threadIdx.x;
  if (tid < LOUT_) pl[tid] = pooled[b * LOUT_ + tid];
  __syncthreads();
  for (int o = tid; o < O_; o += 256) {
    float acc = bd[o];
#pragma unroll 6
    for (int l = 0; l < LOUT_; ++l) acc += pl[l] * Wd[l * O_ + o];
    lg[o] = acc;
  }
  __syncthreads();
  float mx = -3.0e38f;
  for (int o = tid; o < O_; o += 256) mx = fmaxf(mx, lg[o]);
  red[tid] = mx;
  __syncthreads();
  for (int s2 = 128; s2 > 0; s2 >>= 1) {
    if (tid < s2) red[tid] = fmaxf(red[tid], red[tid + s2]);
    __syncthreads();
  }
  mx = red[0];
  __syncthreads();
  float se = 0.f;
  for (int o = tid; o < O_; o += 256) {
    float e = __expf(lg[o] - mx);
    lg[o] = e;
    se += e;
  }
  red[tid] = se;
  __syncthreads();
  for (int s2 = 128; s2 > 0; s2 >>= 1) {
    if (tid < s2) red[tid] += red[tid + s2];
    __syncthreads();
  }
  float inv = 1.f / red[0];
  for (int o = tid; o < O_; o += 256) out[(size_t)b * O_ + o] = lg[o] * inv;
}

extern "C" void kernel_launch(void* const* d_in, const int* in_sizes, int n_in,
                              void* d_out, int out_size, void* d_ws, size_t ws_size,
                              hipStream_t stream) {
  const int* tokens = (const int*)d_in[0];
  const float* emb = (const float*)d_in[1];
  const float* Wq = (const float*)d_in[2];
  const float* bq = (const float*)d_in[3];
  const float* Wk = (const float*)d_in[4];
  const float* bk = (const float*)d_in[5];
  const float* Wv = (const float*)d_in[6];
  const float* bv = (const float*)d_in[7];
  const float* Wo = (const float*)d_in[8];
  const float* bo = (const float*)d_in[9];
  const float* W1 = (const float*)d_in[10];
  const float* b1 = (const float*)d_in[11];
  const float* W2 = (const float*)d_in[12];
  const float* b2 = (const float*)d_in[13];
  const float* Wc = (const float*)d_in[14];
  const float* bc = (const float*)d_in[15];
  const float* Wd = (const float*)d_in[16];
  const float* bd = (const float*)d_in[17];
  float* out = (float*)d_out;

  // ws layout (bytes): X f32 [0,64M) | Ab bf16 [64M,96M) | QKVb [96M,192M)
  // | MH [192M,224M) | Wt [224M,240M) | qkvbias/pooled [240M,...)
  char* ws = (char*)d_ws;
  float* X = (float*)ws;
  __bf16* Ab = (__bf16*)(ws + 67108864);
  __bf16* QKVb = (__bf16*)(ws + 100663296);
  __bf16* FF1b = QKVb;  // reuse (QKV dead after Wo gemm)
  __bf16* MHb = (__bf16*)(ws + 201326592);
  __bf16* Wt = (__bf16*)(ws + 234881024);
  __bf16* Wt_qkv = Wt;                 // [L][1536][512]
  __bf16* Wt_o = Wt + 3145728;         // [L][512][512]
  __bf16* Wt_1 = Wt + 4194304;         // [L][1024][512]
  __bf16* Wt_2 = Wt + 6291456;         // [L][512][1024]
  float* qkvbias = (float*)(ws + 251658240);
  float* pooled = qkvbias + 6144;

  dim3 tb(32, 8);
  transpose_bf16<<<dim3(2, 16, 32), tb, 0, stream>>>(Wq, Wt_qkv + 0,      512, 64, 32768, 786432, 32768);
  transpose_bf16<<<dim3(2, 16, 32), tb, 0, stream>>>(Wk, Wt_qkv + 262144, 512, 64, 32768, 786432, 32768);
  transpose_bf16<<<dim3(2, 16, 32), tb, 0, stream>>>(Wv, Wt_qkv + 524288, 512, 64, 32768, 786432, 32768);
  transpose_bf16<<<dim3(16, 16, 4), tb, 0, stream>>>(Wo, Wt_o, 512, 512, 262144, 0, 262144);
  transpose_bf16<<<dim3(32, 16, 4), tb, 0, stream>>>(W1, Wt_1, 512, 1024, 524288, 0, 524288);
  transpose_bf16<<<dim3(16, 32, 4), tb, 0, stream>>>(W2, Wt_2, 1024, 512, 524288, 0, 524288);
  bias_concat<<<dim3(24), dim3(256), 0, stream>>>(bq, bk, bv, qkvbias);

  embed_kernel<<<dim3(BS_ * E_ / 4 / 256), dim3(256), 0, stream>>>(tokens, emb, X, Ab);

  dim3 blk(256);
  for (int i = 0; i < L_; ++i) {
    gemm_bf16<0, 0, 0, 1, 1, 16><<<dim3(256 * 12), blk, 0, stream>>>(
        Ab, Wt_qkv + (size_t)i * 786432, qkvbias + i * QS_, nullptr, nullptr,
        QKVb, QS_, 512, 12);
    attn_bf16<<<dim3(1024), blk, 0, stream>>>(QKVb);
    gemm_bf16<0, 0, 0, 1, 0, 16><<<dim3(256 * 4), blk, 0, stream>>>(
        QKVb, Wt_o + (size_t)i * 262144, bo + i * E_, nullptr, nullptr, MHb,
        512, QS_, 4);
    addnorm_kernel<<<dim3(BS_ / 4), blk, 0, stream>>>(X, MHb, Ab);
    gemm_bf16<1, 0, 0, 1, 0, 16><<<dim3(256 * 8), blk, 0, stream>>>(
        Ab, Wt_1 + (size_t)i * 524288, b1 + (size_t)i * 2 * E_, nullptr, nullptr,
        FF1b, 1024, 512, 8);
    gemm_bf16<0, 1, 1, 1, 0, 32><<<dim3(256 * 4), blk, 0, stream>>>(
        FF1b, Wt_2 + (size_t)i * 524288, b2 + (size_t)i * E_, X, X, Ab,
        512, 1024, 4);
  }
  conv_pool_kernel<<<dim3(BS_ * LOUT_ / S_ / 4), blk, 0, stream>>>(X, Wc, bc, pooled);
  dense_softmax_kernel<<<dim3(B_), blk, 0, stream>>>(pooled, Wd, bd, out);
}

// Round 11
// 1375.400 us; speedup vs baseline: 1.0437x; 1.0111x over previous
//
#include <hip/hip_runtime.h>
#include <cstddef>

constexpr int B_ = 64, S_ = 512, E_ = 512, H_ = 8, D_ = 64, L_ = 4, O_ = 1000;
constexpr int BS_ = B_ * S_;        // 32768
constexpr int HD_ = H_ * D_;        // 512
constexpr int QS_ = 1536;           // fused QKV row stride
constexpr int LOUT_ = 102;
constexpr float SCALE_ = 0.04419417382415922f;  // 1/sqrt(512)

typedef __bf16 bf16x8 __attribute__((ext_vector_type(8)));
typedef __bf16 bf16x4 __attribute__((ext_vector_type(4)));
typedef __bf16 bf16x2 __attribute__((ext_vector_type(2)));
typedef float floatx4 __attribute__((ext_vector_type(4)));

__device__ inline void load16_lds(const __bf16* g, __bf16* l) {
  __builtin_amdgcn_global_load_lds(
      (const __attribute__((address_space(1))) void*)g,
      (__attribute__((address_space(3))) void*)l, 16, 0, 0);
}

// ---------------- weight transpose + bf16 convert ----------------
__global__ __launch_bounds__(256) void transpose_bf16(
    const float* __restrict__ in, __bf16* __restrict__ out,
    int R, int C, int IZ, int OZL, int OZH) {
  __shared__ float t[32][33];
  int z = blockIdx.z;
  const float* inz = in + (size_t)z * IZ;
  __bf16* outz = out + (size_t)(z >> 3) * OZL + (size_t)(z & 7) * OZH;
  int c0 = blockIdx.x * 32, r0 = blockIdx.y * 32;
  int x = threadIdx.x, y = threadIdx.y;  // (32,8)
#pragma unroll
  for (int j = 0; j < 32; j += 8) t[y + j][x] = inz[(size_t)(r0 + y + j) * C + c0 + x];
  __syncthreads();
#pragma unroll
  for (int j = 0; j < 32; j += 8)
    outz[(size_t)(c0 + y + j) * R + r0 + x] = (__bf16)t[x][y + j];
}

// ---------------- concat qkv bias: [L][1536] = bq|bk|bv ----------------
__global__ __launch_bounds__(256) void bias_concat(
    const float* __restrict__ bq, const float* __restrict__ bk,
    const float* __restrict__ bv, float* __restrict__ qkvb) {
  int idx = blockIdx.x * 256 + threadIdx.x;  // < 6144
  int l = idx / QS_, j = idx % QS_;
  float v;
  if (j < 512) v = bq[l * 512 + j];
  else if (j < 1024) v = bk[l * 512 + j - 512];
  else v = bv[l * 512 + j - 1024];
  qkvb[idx] = v;
}

// ---------------- embedding + mask -> X fp32 + Ab bf16 ----------------
__global__ __launch_bounds__(256) void embed_kernel(
    const int* __restrict__ tokens, const float* __restrict__ emb,
    float* __restrict__ X, __bf16* __restrict__ Ab) {
  int idx = blockIdx.x * 256 + threadIdx.x;  // float4 index
  int bs = idx >> 7;
  int e = (idx & 127) << 2;
  int tok = tokens[bs];
  float4 v;
  if (tok == 0) v = make_float4(0.f, 0.f, 0.f, 0.f);
  else v = *(const float4*)(emb + (size_t)tok * E_ + e);
  size_t off = (size_t)bs * E_ + e;
  *(float4*)(X + off) = v;
  bf16x4 b;
  b[0] = (__bf16)v.x; b[1] = (__bf16)v.y; b[2] = (__bf16)v.z; b[3] = (__bf16)v.w;
  *(bf16x4*)(Ab + off) = b;
}

// ---------------- bf16 MFMA GEMM, ring-3 LDS + counted vmcnt (T4) ------
// CONFIG OF RECORD (R7: 70.6us QKV, best total 1390.0).  Measured-negative
// probes, do not revisit: setprio (R4, -15us); coarse 256^2 BK=32 (R6,
// -12%); faithful 4-phase 256^2 / 128KB dynamic LDS (R8, -8%; K=512
// amortizes the pipeline poorly per m248v2's K>=1024 regime); ring-2 at
// 4 blocks/CU (R9, depth-1 prefetch loses more than TLP gains).
// Ledger: iter kt stages buf[(kt+2)%3] (last read at kt-1, next read kt+2;
// a barrier separates every read-set from the overwriting issue).
// vmcnt(8) leaves the 2 newer K-steps (4 loads each) in flight => step kt
// has landed.  Tail: 8 -> 4 -> 0.  Never 0 mid-loop.
template <int RELU, int RES, int OUTF, int OUTB, int SCQ, int KT>
__global__ __launch_bounds__(256) void gemm_bf16(
    const __bf16* __restrict__ A, const __bf16* __restrict__ Bt,
    const float* __restrict__ bias, const float* __restrict__ Rsd,
    float* __restrict__ Cf, __bf16* __restrict__ Cb, int N, int lda, int Nt) {
  // ring: A[3][128][32] at [0,12288), B[3][128][32] at [12288,24576); Cs overlay
  __shared__ __align__(16) __bf16 smem[24576];  // 48 KB
  int tid = threadIdx.x;
  int lane = tid & 63, w = tid >> 6;
  // XCD-aware swizzle: xcd owns a contiguous m-range (= contiguous batches)
  int Mt8 = (int)(gridDim.x / Nt) >> 3;       // m-tiles per XCD range
  int xcd = blockIdx.x & 7;
  int j = blockIdx.x >> 3;
  int rr = j % (2 * Nt), chunk = j / (2 * Nt);
  int mt = xcd * Mt8 + chunk * 2 + (rr & 1);
  int nt = rr >> 1;
  int m0 = mt * 128, n0 = nt * 128;
  int q4 = lane >> 4, a_ = lane & 15;
  const int ldb = KT * 32;
  int r0s = tid >> 2, q0s = (tid & 3) ^ ((r0s >> 1) & 3);
  int r1s = 64 + (tid >> 2), q1s = (tid & 3) ^ ((r1s >> 1) & 3);
  const __bf16* Ag = A + (size_t)m0 * lda;
  const __bf16* Bg = Bt + (size_t)n0 * ldb;

  floatx4 acc[4][4];
#pragma unroll
  for (int i = 0; i < 4; ++i)
#pragma unroll
    for (int jj = 0; jj < 4; ++jj) acc[i][jj] = (floatx4)(0.0f);

  auto STAGE = [&](int kt, int bs) {
    __bf16* Ad = smem + bs * 4096;
    __bf16* Bd = smem + 12288 + bs * 4096;
    int k0 = kt * 32;
    load16_lds(Ag + (size_t)r0s * lda + k0 + q0s * 8, Ad + tid * 8);
    load16_lds(Ag + (size_t)r1s * lda + k0 + q1s * 8, Ad + (256 + tid) * 8);
    load16_lds(Bg + (size_t)r0s * ldb + k0 + q0s * 8, Bd + tid * 8);
    load16_lds(Bg + (size_t)r1s * ldb + k0 + q1s * 8, Bd + (256 + tid) * 8);
  };

  STAGE(0, 0);
  if (KT > 1) STAGE(1, 1);
#pragma unroll
  for (int kt = 0; kt < KT; ++kt) {
    if (kt + 2 < KT) {
      STAGE(kt + 2, (kt + 2) % 3);
      asm volatile("s_waitcnt vmcnt(8)" ::: "memory");
    } else if (kt + 1 < KT) {
      asm volatile("s_waitcnt vmcnt(4)" ::: "memory");
    } else {
      asm volatile("s_waitcnt vmcnt(0)" ::: "memory");
    }
    __builtin_amdgcn_s_barrier();
    __builtin_amdgcn_sched_barrier(0);
    const __bf16* As = smem + (kt % 3) * 4096;
    const __bf16* Bs = smem + 12288 + (kt % 3) * 4096;
    bf16x8 af[4], bfr[4];
#pragma unroll
    for (int i = 0; i < 4; ++i) {
      int row = (w & 1) * 64 + i * 16 + a_;
      int pc = q4 ^ ((row >> 1) & 3);
      af[i] = *(const bf16x8*)&As[(row * 4 + pc) * 8];
    }
#pragma unroll
    for (int jc = 0; jc < 4; ++jc) {
      int row = (w >> 1) * 64 + jc * 16 + a_;
      int pc = q4 ^ ((row >> 1) & 3);
      bfr[jc] = *(const bf16x8*)&Bs[(row * 4 + pc) * 8];
    }
#pragma unroll
    for (int i = 0; i < 4; ++i)
#pragma unroll
      for (int jc = 0; jc < 4; ++jc)
        acc[i][jc] = __builtin_amdgcn_mfma_f32_16x16x32_bf16(bfr[jc], af[i],
                                                             acc[i][jc], 0, 0, 0);
    asm volatile("" ::: "memory");
    __builtin_amdgcn_s_barrier();
  }
  // ---- epilogue: vectorized, bf16 staged via LDS ----
#pragma unroll
  for (int i = 0; i < 4; ++i) {
    int ml = (w & 1) * 64 + i * 16 + a_;
    int m = m0 + ml;
#pragma unroll
    for (int jc = 0; jc < 4; ++jc) {
      int nl = (w >> 1) * 64 + jc * 16 + q4 * 4;
      int n = n0 + nl;
      float4 bi = *(const float4*)(bias + n);
      floatx4 v = acc[i][jc];
      v[0] += bi.x; v[1] += bi.y; v[2] += bi.z; v[3] += bi.w;
      if (SCQ) { if (n < 512) v *= SCALE_; }
      if (RES) {
        float4 rv = *(const float4*)(Rsd + (size_t)m * N + n);
        v[0] += rv.x; v[1] += rv.y; v[2] += rv.z; v[3] += rv.w;
      }
      if (RELU) {
#pragma unroll
        for (int r = 0; r < 4; ++r) v[r] = fmaxf(v[r], 0.f);
      }
      if (OUTF) {
        float4 o = make_float4(v[0], v[1], v[2], v[3]);
        *(float4*)(Cf + (size_t)m * N + n) = o;
      }
      if (OUTB) {
        bf16x4 ob;
#pragma unroll
        for (int r = 0; r < 4; ++r) ob[r] = (__bf16)v[r];
        *(bf16x4*)&smem[ml * 136 + nl] = ob;
      }
    }
  }
  if (OUTB) {
    __syncthreads();
#pragma unroll
    for (int it = 0; it < 8; ++it) {
      int cid = it * 256 + tid;
      int row = cid >> 4, c8 = cid & 15;
      bf16x8 val = *(const bf16x8*)&smem[row * 136 + c8 * 8];
      *(bf16x8*)(Cb + (size_t)(m0 + row) * N + n0 + c8 * 8) = val;
    }
  }
}

// ---------------- MFMA flash attention v2 (S^T layout, swizzled LDS) ------
// CONFIG OF RECORD (R7: 70.6-70.8us/dispatch, FETCH 49.2MB).  Measured-
// negative probes, do not revisit: occupancy 3-4 blocks/CU (R1/R3, collapses
// the L2 equilibrium, 2.6x dur); setprio (R9, -8.7us, barrier-lockstep
// waves); K/V double-buffer + T14 split (R10, +7.6us, mechanism undiagnosed).
// Wins kept: 256-row slab; producer-aligned XCD decode (gemm XCD x owns
// rows [x*4096,(x+1)*4096) = batches [8x,8x+8)): b = xg*8 + (slot>>4).
__global__ __launch_bounds__(256, 2) void attn_bf16(__bf16* __restrict__ QKV) {
  __shared__ __align__(16) __bf16 Qs[256 * 64];  // swizzled chunks
  __shared__ __align__(16) __bf16 Ks[64 * 64];   // swizzled
  __shared__ __align__(16) __bf16 Vt[64 * 64];   // V^T [d][t], swizzled
  __shared__ __align__(16) __bf16 Ps[64 * 64];   // P [s][t], swizzled
  int tid = threadIdx.x, lane = tid & 63, w = tid >> 6;
  int q4 = lane >> 4, a_ = lane & 15;
  int bid = blockIdx.x;
  int xg = bid & 7, slot = bid >> 3;
  int b = xg * 8 + (slot >> 4);
  int r_ = slot & 15;
  int h = r_ >> 1;
  int s0 = (r_ & 1) * 256;
  size_t rowbase = (size_t)b * S_ * QS_ + h * 64;
  __bf16* Qg = QKV + rowbase;
  const __bf16* Kg = QKV + rowbase + 512;
  const __bf16* Vg = QKV + rowbase + 1024;
  // stage Q slab (256 rows), swizzled
#pragma unroll
  for (int j = 0; j < 8; ++j) {
    int ci = j * 256 + w * 64 + lane;
    int row = ci >> 3, c = ci & 7, q = c ^ (row & 7);
    load16_lds(Qg + (size_t)(s0 + row) * QS_ + q * 8, Qs + (j * 256 + w * 64) * 8);
  }
  float mrow[4], lrow[4];
  floatx4 accO[4][4];
#pragma unroll
  for (int cc = 0; cc < 4; ++cc) {
    mrow[cc] = -3.0e38f; lrow[cc] = 0.f;
#pragma unroll
    for (int jc = 0; jc < 4; ++jc) accO[cc][jc] = (floatx4)(0.0f);
  }

  for (int t0 = 0; t0 < S_; t0 += 64) {
    // stage K tile, swizzled
#pragma unroll
    for (int j = 0; j < 2; ++j) {
      int ci = j * 256 + w * 64 + lane;
      int row = ci >> 3, c = ci & 7, q = c ^ (row & 7);
      load16_lds(Kg + (size_t)(t0 + row) * QS_ + q * 8, Ks + (j * 256 + w * 64) * 8);
    }
    // stage V transposed -> Vt[d][t], swizzled chunks
    {
      int tp = tid & 31, dg = tid >> 5;
      bf16x8 v0 = *(const bf16x8*)(Vg + (size_t)(t0 + 2 * tp) * QS_ + dg * 8);
      bf16x8 v1 = *(const bf16x8*)(Vg + (size_t)(t0 + 2 * tp + 1) * QS_ + dg * 8);
#pragma unroll
      for (int x = 0; x < 8; ++x) {
        int d = dg * 8 + x;
        bf16x2 p; p[0] = v0[x]; p[1] = v1[x];
        *(bf16x2*)&Vt[(d * 8 + ((tp >> 2) ^ (d & 7))) * 8 + (tp & 3) * 2] = p;
      }
    }
    __syncthreads();
    // K and V^T fragments (shared across the 4 s-chunks)
    bf16x8 af[2][4], bv[2][4];
#pragma unroll
    for (int ks = 0; ks < 2; ++ks)
#pragma unroll
      for (int jc = 0; jc < 4; ++jc) {
        int row = jc * 16 + a_, q = ks * 4 + q4;
        af[ks][jc] = *(const bf16x8*)&Ks[(row * 8 + (q ^ (row & 7))) * 8];
        bv[ks][jc] = *(const bf16x8*)&Vt[(row * 8 + (q ^ (row & 7))) * 8];
      }
#pragma unroll
    for (int cc = 0; cc < 4; ++cc) {
      int sbase = (cc * 4 + w) * 16;
      // S^T = K Q^T : rows t = jc*16+q4*4+r, col s = sbase + a_
      floatx4 sc[4];
#pragma unroll
      for (int jc = 0; jc < 4; ++jc) sc[jc] = (floatx4)(0.0f);
#pragma unroll
      for (int ks = 0; ks < 2; ++ks) {
        int row = sbase + a_, q = ks * 4 + q4;
        bf16x8 bq = *(const bf16x8*)&Qs[(row * 8 + (q ^ (row & 7))) * 8];
#pragma unroll
        for (int jc = 0; jc < 4; ++jc)
          sc[jc] = __builtin_amdgcn_mfma_f32_16x16x32_bf16(af[ks][jc], bq,
                                                           sc[jc], 0, 0, 0);
      }
      // online softmax: per lane, all 16 values share column s = sbase+a_
      float mx = sc[0][0];
#pragma unroll
      for (int jc = 0; jc < 4; ++jc)
#pragma unroll
        for (int r = 0; r < 4; ++r) mx = fmaxf(mx, sc[jc][r]);
      mx = fmaxf(mx, __shfl_xor(mx, 16));
      mx = fmaxf(mx, __shfl_xor(mx, 32));
      float mnew = fmaxf(mrow[cc], mx);
      float alpha = __expf(mrow[cc] - mnew);
      mrow[cc] = mnew;
      float ps = 0.f;
      int prow = w * 16 + a_;
#pragma unroll
      for (int jc = 0; jc < 4; ++jc) {
        bf16x4 pb;
#pragma unroll
        for (int r = 0; r < 4; ++r) {
          float p = __expf(sc[jc][r] - mnew);
          ps += p;
          pb[r] = (__bf16)p;
        }
        int pc = jc * 2 + (q4 >> 1);
        *(bf16x4*)&Ps[(prow * 8 + (pc ^ (prow & 7))) * 8 + (q4 & 1) * 4] = pb;
      }
      ps += __shfl_xor(ps, 16);
      ps += __shfl_xor(ps, 32);
      lrow[cc] = lrow[cc] * alpha + ps;
      float aal[4];
#pragma unroll
      for (int r = 0; r < 4; ++r) aal[r] = __shfl(alpha, q4 * 4 + r);
#pragma unroll
      for (int jc = 0; jc < 4; ++jc) {
        floatx4 t = accO[cc][jc];
#pragma unroll
        for (int r = 0; r < 4; ++r) t[r] *= aal[r];
        accO[cc][jc] = t;
      }
      // O += P V  (Ps rows wave-private; same-wave LDS RAW ordered via lgkmcnt)
#pragma unroll
      for (int ks = 0; ks < 2; ++ks) {
        int q = ks * 4 + q4;
        bf16x8 ap = *(const bf16x8*)&Ps[(prow * 8 + (q ^ (prow & 7))) * 8];
#pragma unroll
        for (int jc = 0; jc < 4; ++jc)
          accO[cc][jc] = __builtin_amdgcn_mfma_f32_16x16x32_bf16(
              ap, bv[ks][jc], accO[cc][jc], 0, 0, 0);
      }
    }
    __syncthreads();
  }
  // epilogue: row = s0+(cc*4+w)*16+q4*4+r, col = jc*16+a_  (into Q slice)
#pragma unroll
  for (int cc = 0; cc < 4; ++cc) {
    float inv = 1.f / lrow[cc];
    float linv[4];
#pragma unroll
    for (int r = 0; r < 4; ++r) linv[r] = __shfl(inv, q4 * 4 + r);
    int srow = s0 + (cc * 4 + w) * 16 + q4 * 4;
#pragma unroll
    for (int r = 0; r < 4; ++r)
#pragma unroll
      for (int jc = 0; jc < 4; ++jc)
        Qg[(size_t)(srow + r) * QS_ + jc * 16 + a_] =
            (__bf16)(accO[cc][jc][r] * linv[r]);
  }
}

// ---------------- add + l2norm: X = l2norm(X + MH), Ab = bf16(X) ----------
__global__ __launch_bounds__(256) void addnorm_kernel(
    float* __restrict__ X, const __bf16* __restrict__ MH, __bf16* __restrict__ Ab) {
  int row = blockIdx.x * 4 + (threadIdx.x >> 6);
  int ln = threadIdx.x & 63;
  size_t off = (size_t)row * E_ + ln * 8;
  float xv[8];
  *(float4*)&xv[0] = *(const float4*)(X + off);
  *(float4*)&xv[4] = *(const float4*)(X + off + 4);
  bf16x8 mh = *(const bf16x8*)(MH + off);
  float ss = 0.f;
#pragma unroll
  for (int j = 0; j < 8; ++j) {
    xv[j] += (float)mh[j];
    ss += xv[j] * xv[j];
  }
#pragma unroll
  for (int o = 1; o < 64; o <<= 1) ss += __shfl_xor(ss, o);
  float inv = rsqrtf(fmaxf(ss, 1e-12f));
  bf16x8 ob;
#pragma unroll
  for (int j = 0; j < 8; ++j) {
    xv[j] *= inv;
    ob[j] = (__bf16)xv[j];
  }
  *(float4*)(X + off) = *(float4*)&xv[0];
  *(float4*)(X + off + 4) = *(float4*)&xv[4];
  *(bf16x8*)(Ab + off) = ob;
}

// ---------------- conv-pool: pooled[b][l] = dot(X[b, 5l:5l+5, :], Wc)+bc ---
__global__ __launch_bounds__(256) void conv_pool_kernel(
    const float* __restrict__ X, const float* __restrict__ Wc,
    const float* __restrict__ bc, float* __restrict__ pooled) {
  int wid = blockIdx.x * 4 + (threadIdx.x >> 6);
  int ln = threadIdx.x & 63;
  int b = wid / LOUT_, l = wid % LOUT_;
  const float* xr = X + (size_t)b * S_ * E_ + (size_t)l * 5 * E_;
  float v = 0.f;
#pragma unroll
  for (int j = 0; j < 10; ++j) {
    int i = (j * 64 + ln) * 4;
    float4 x4 = *(const float4*)(xr + i);
    float4 w4 = *(const float4*)(Wc + i);
    v += x4.x * w4.x + x4.y * w4.y + x4.z * w4.z + x4.w * w4.w;
  }
#pragma unroll
  for (int o = 32; o >= 1; o >>= 1) v += __shfl_down(v, o);
  if (ln == 0) pooled[b * LOUT_ + l] = v + bc[0];
}

// ---------------- dense + softmax: out[b] = softmax(pooled[b] @ Wd + bd) ---
__global__ __launch_bounds__(256) void dense_softmax_kernel(
    const float* __restrict__ pooled, const float* __restrict__ Wd,
    const float* __restrict__ bd, float* __restrict__ out) {
  __shared__ float pl[LOUT_];
  __shared__ float red[256];
  __shared__ float lg[O_];
  int b = blockIdx.x, tid = threadIdx.x;
  if (tid < LOUT_) pl[tid] = pooled[b * LOUT_ + tid];
  __syncthreads();
  for (int o = tid; o < O_; o += 256) {
    float acc = bd[o];
#pragma unroll 6
    for (int l = 0; l < LOUT_; ++l) acc += pl[l] * Wd[l * O_ + o];
    lg[o] = acc;
  }
  __syncthreads();
  float mx = -3.0e38f;
  for (int o = tid; o < O_; o += 256) mx = fmaxf(mx, lg[o]);
  red[tid] = mx;
  __syncthreads();
  for (int s2 = 128; s2 > 0; s2 >>= 1) {
    if (tid < s2) red[tid] = fmaxf(red[tid], red[tid + s2]);
    __syncthreads();
  }
  mx = red[0];
  __syncthreads();
  float se = 0.f;
  for (int o = tid; o < O_; o += 256) {
    float e = __expf(lg[o] - mx);
    lg[o] = e;
    se += e;
  }
  red[tid] = se;
  __syncthreads();
  for (int s2 = 128; s2 > 0; s2 >>= 1) {
    if (tid < s2) red[tid] += red[tid + s2];
    __syncthreads();
  }
  float inv = 1.f / red[0];
  for (int o = tid; o < O_; o += 256) out[(size_t)b * O_ + o] = lg[o] * inv;
}

extern "C" void kernel_launch(void* const* d_in, const int* in_sizes, int n_in,
                              void* d_out, int out_size, void* d_ws, size_t ws_size,
                              hipStream_t stream) {
  const int* tokens = (const int*)d_in[0];
  const float* emb = (const float*)d_in[1];
  const float* Wq = (const float*)d_in[2];
  const float* bq = (const float*)d_in[3];
  const float* Wk = (const float*)d_in[4];
  const float* bk = (const float*)d_in[5];
  const float* Wv = (const float*)d_in[6];
  const float* bv = (const float*)d_in[7];
  const float* Wo = (const float*)d_in[8];
  const float* bo = (const float*)d_in[9];
  const float* W1 = (const float*)d_in[10];
  const float* b1 = (const float*)d_in[11];
  const float* W2 = (const float*)d_in[12];
  const float* b2 = (const float*)d_in[13];
  const float* Wc = (const float*)d_in[14];
  const float* bc = (const float*)d_in[15];
  const float* Wd = (const float*)d_in[16];
  const float* bd = (const float*)d_in[17];
  float* out = (float*)d_out;

  // ws layout (bytes): X f32 [0,64M) | Ab bf16 [64M,96M) | QKVb [96M,192M)
  // | MH [192M,224M) | Wt [224M,240M) | qkvbias/pooled [240M,...)
  char* ws = (char*)d_ws;
  float* X = (float*)ws;
  __bf16* Ab = (__bf16*)(ws + 67108864);
  __bf16* QKVb = (__bf16*)(ws + 100663296);
  __bf16* FF1b = QKVb;  // reuse (QKV dead after Wo gemm)
  __bf16* MHb = (__bf16*)(ws + 201326592);
  __bf16* Wt = (__bf16*)(ws + 234881024);
  __bf16* Wt_qkv = Wt;                 // [L][1536][512]
  __bf16* Wt_o = Wt + 3145728;         // [L][512][512]
  __bf16* Wt_1 = Wt + 4194304;         // [L][1024][512]
  __bf16* Wt_2 = Wt + 6291456;         // [L][512][1024]
  float* qkvbias = (float*)(ws + 251658240);
  float* pooled = qkvbias + 6144;

  dim3 tb(32, 8);
  transpose_bf16<<<dim3(2, 16, 32), tb, 0, stream>>>(Wq, Wt_qkv + 0,      512, 64, 32768, 786432, 32768);
  transpose_bf16<<<dim3(2, 16, 32), tb, 0, stream>>>(Wk, Wt_qkv + 262144, 512, 64, 32768, 786432, 32768);
  transpose_bf16<<<dim3(2, 16, 32), tb, 0, stream>>>(Wv, Wt_qkv + 524288, 512, 64, 32768, 786432, 32768);
  transpose_bf16<<<dim3(16, 16, 4), tb, 0, stream>>>(Wo, Wt_o, 512, 512, 262144, 0, 262144);
  transpose_bf16<<<dim3(32, 16, 4), tb, 0, stream>>>(W1, Wt_1, 512, 1024, 524288, 0, 524288);
  transpose_bf16<<<dim3(16, 32, 4), tb, 0, stream>>>(W2, Wt_2, 1024, 512, 524288, 0, 524288);
  bias_concat<<<dim3(24), dim3(256), 0, stream>>>(bq, bk, bv, qkvbias);

  embed_kernel<<<dim3(BS_ * E_ / 4 / 256), dim3(256), 0, stream>>>(tokens, emb, X, Ab);

  dim3 blk(256);
  for (int i = 0; i < L_; ++i) {
    gemm_bf16<0, 0, 0, 1, 1, 16><<<dim3(256 * 12), blk, 0, stream>>>(
        Ab, Wt_qkv + (size_t)i * 786432, qkvbias + i * QS_, nullptr, nullptr,
        QKVb, QS_, 512, 12);
    attn_bf16<<<dim3(1024), blk, 0, stream>>>(QKVb);
    gemm_bf16<0, 0, 0, 1, 0, 16><<<dim3(256 * 4), blk, 0, stream>>>(
        QKVb, Wt_o + (size_t)i * 262144, bo + i * E_, nullptr, nullptr, MHb,
        512, QS_, 4);
    addnorm_kernel<<<dim3(BS_ / 4), blk, 0, stream>>>(X, MHb, Ab);
    gemm_bf16<1, 0, 0, 1, 0, 16><<<dim3(256 * 8), blk, 0, stream>>>(
        Ab, Wt_1 + (size_t)i * 524288, b1 + (size_t)i * 2 * E_, nullptr, nullptr,
        FF1b, 1024, 512, 8);
    gemm_bf16<0, 1, 1, 1, 0, 32><<<dim3(256 * 4), blk, 0, stream>>>(
        FF1b, Wt_2 + (size_t)i * 524288, b2 + (size_t)i * E_, X, X, Ab,
        512, 1024, 4);
  }
  conv_pool_kernel<<<dim3(BS_ * LOUT_ / S_ / 4), blk, 0, stream>>>(X, Wc, bc, pooled);
  dense_softmax_kernel<<<dim3(B_), blk, 0, stream>>>(pooled, Wd, bd, out);
}